// Round 4
// baseline (1093.097 us; speedup 1.0000x reference)
//
#include <hip/hip_runtime.h>
#include <stdint.h>

typedef unsigned short ushort_t;

__device__ __forceinline__ float bf2f(unsigned short u) {
  union { unsigned int i; float f; } c; c.i = ((unsigned int)u) << 16; return c.f;
}
__device__ __forceinline__ unsigned short f2bf(float f) {
  union { float f; unsigned int i; } c; c.f = f;
  unsigned int r = c.i + 0x7FFFu + ((c.i >> 16) & 1u);
  return (unsigned short)(r >> 16);
}
// NaN-propagating relu (tripwire: NaN stays visible)
__device__ __forceinline__ float relu_nanprop(float v) { return (v < 0.f) ? 0.f : v; }

typedef __attribute__((ext_vector_type(8))) short s16x8;
typedef __attribute__((ext_vector_type(4))) float f32x4;

// ---------------- zero scratch ints ----------------
__global__ void zero_kernel(int* __restrict__ p, int n) {
  for (int i = blockIdx.x * blockDim.x + threadIdx.x; i < n; i += gridDim.x * blockDim.x)
    p[i] = 0;
}

// ---------------- float32-vs-bf16 detection on x0 ----------------
// float32: low 16 bits of each word are random mantissa bits -> "exponent" field uniform.
// bf16-pairs from ~N(0,1): low half-word is a bf16 with exponent in ~[96,144].
__global__ void detect_f32_kernel(const unsigned int* __restrict__ x, int* __restrict__ flagF, int nw) {
  __shared__ int cnt;
  if (threadIdx.x == 0) cnt = 0;
  __syncthreads();
  int local = 0;
  for (int i = threadIdx.x; i < 4096 && i < nw; i += blockDim.x) {
    unsigned int low = x[i] & 0xFFFFu;
    unsigned int e = (low >> 7) & 0xFFu;
    if (low != 0u && (e < 96u || e > 144u)) local++;
  }
  atomicAdd(&cnt, local);
  __syncthreads();
  if (threadIdx.x == 0) flagF[0] = (cnt > 1024) ? 1 : 0;  // 1 => float32 inputs
}

// ---------------- edge dtype detection (int64 vs int32) ----------------
__global__ void detect_kernel(const int* __restrict__ e32, int* __restrict__ flag, int n32) {
  __shared__ int any;
  if (threadIdx.x == 0) any = 0;
  __syncthreads();
  for (int i = threadIdx.x; i < 4096; i += blockDim.x) {
    int idx = 2 * i + 1;
    if (idx < n32 && e32[idx] != 0) any = 1;
  }
  __syncthreads();
  if (threadIdx.x == 0) flag[0] = (any == 0) ? 1 : 0;  // 1 => int64
}

__device__ __forceinline__ int edge_at(const void* edges, int wide, int idx) {
  if (wide) return (int)((const long long*)edges)[idx];
  return ((const int*)edges)[idx];
}

// ---------------- convert input (float32 or bf16) -> bf16 ----------------
__global__ void cvt_kernel(const void* __restrict__ in, ushort_t* __restrict__ out,
                           int n, const int* __restrict__ flagF) {
  int f = flagF[0];
  for (int i = blockIdx.x * blockDim.x + threadIdx.x; i < n; i += gridDim.x * blockDim.x)
    out[i] = f ? f2bf(((const float*)in)[i]) : ((const ushort_t*)in)[i];
}

// ---------------- convert + transpose: W[K][C] -> WT[C][K] bf16 ----------------
__global__ void cvt_transpose_kernel(const void* __restrict__ W, ushort_t* __restrict__ WT,
                                     int K, int C, const int* __restrict__ flagF) {
  int f = flagF[0];
  int i = blockIdx.x * blockDim.x + threadIdx.x;
  if (i < K * C) {
    int k = i / C, c = i - k * C;
    ushort_t v = f ? f2bf(((const float*)W)[i]) : ((const ushort_t*)W)[i];
    WT[c * K + k] = v;
  }
}

// ---------------- CSR build ----------------
__global__ void hist_kernel(const void* __restrict__ edges, const int* __restrict__ flag,
                            int* __restrict__ deg, int E, int Nn) {
  int wide = flag[0];
  for (int e = blockIdx.x * blockDim.x + threadIdx.x; e < E; e += gridDim.x * blockDim.x) {
    int d = edge_at(edges, wide, E + e);
    if (d < 0) d = 0; if (d >= Nn) d = Nn - 1;
    atomicAdd(&deg[d], 1);
  }
}

__global__ void scan_kernel(const int* __restrict__ deg, int* __restrict__ offs, int n) {
  __shared__ int tmp[256];
  __shared__ int carry;
  int t = threadIdx.x;
  if (t == 0) carry = 0;
  __syncthreads();
  for (int base = 0; base < n; base += 256) {
    int i = base + t;
    int v = (i < n) ? deg[i] : 0;
    tmp[t] = v;
    __syncthreads();
    for (int off = 1; off < 256; off <<= 1) {
      int x = (t >= off) ? tmp[t - off] : 0;
      __syncthreads();
      tmp[t] += x;
      __syncthreads();
    }
    if (i < n) offs[i] = carry + tmp[t] - v;
    __syncthreads();
    if (t == 0) carry += tmp[255];
    __syncthreads();
  }
  if (t == 0) offs[n] = carry;
}

__global__ void scatter_kernel(const void* __restrict__ edges, const int* __restrict__ flag,
                               const int* __restrict__ offs, int* __restrict__ fill,
                               int* __restrict__ srcS, int E, int Nn) {
  int wide = flag[0];
  for (int e = blockIdx.x * blockDim.x + threadIdx.x; e < E; e += gridDim.x * blockDim.x) {
    int s = edge_at(edges, wide, e);
    int d = edge_at(edges, wide, E + e);
    if (d < 0) d = 0; if (d >= Nn) d = Nn - 1;
    if (s < 0) s = 0; if (s >= Nn) s = Nn - 1;
    int p = offs[d] + atomicAdd(&fill[d], 1);
    if (p < 0) p = 0; if (p >= E) p = E - 1;
    srcS[p] = s;
  }
}

// ---------------- GEMM: C[M][NC] = A[M][K] * BT[NC][K]^T, bf16 out (+opt bias) ----------------
__global__ __launch_bounds__(256)
void gemm_kernel(const ushort_t* __restrict__ A, const ushort_t* __restrict__ BT,
                 ushort_t* __restrict__ Cb, const ushort_t* __restrict__ bias,
                 int M, int K, int NC) {
  __shared__ __align__(16) ushort_t As[128 * 32];
  __shared__ __align__(16) ushort_t Bs[128 * 32];
  int tid = threadIdx.x;
  int lane = tid & 63, wave = tid >> 6;
  int tm = blockIdx.x * 128, tn = blockIdx.y * 128;
  int wm = (wave >> 1) * 64, wn = (wave & 1) * 64;
  int q = lane >> 4, l = lane & 15;
  f32x4 acc[4][4];
#pragma unroll
  for (int a = 0; a < 4; a++)
#pragma unroll
    for (int b = 0; b < 4; b++) acc[a][b] = (f32x4){0.f, 0.f, 0.f, 0.f};

  for (int k0 = 0; k0 < K; k0 += 32) {
#pragma unroll
    for (int t = 0; t < 2; t++) {
      int u = t * 256 + tid;
      int row = u >> 2, c8 = (u & 3) * 8;
      int ra = tm + row; if (ra > M - 1) ra = M - 1;
      *(uint4*)&As[row * 32 + c8] = *(const uint4*)&A[(size_t)ra * K + k0 + c8];
      *(uint4*)&Bs[row * 32 + c8] = *(const uint4*)&BT[(size_t)(tn + row) * K + k0 + c8];
    }
    __syncthreads();
    s16x8 af[4], bfr[4];
#pragma unroll
    for (int mf = 0; mf < 4; mf++) af[mf] = *(const s16x8*)&As[(wm + mf * 16 + l) * 32 + q * 8];
#pragma unroll
    for (int nf = 0; nf < 4; nf++) bfr[nf] = *(const s16x8*)&Bs[(wn + nf * 16 + l) * 32 + q * 8];
#pragma unroll
    for (int mf = 0; mf < 4; mf++)
#pragma unroll
      for (int nf = 0; nf < 4; nf++)
        acc[mf][nf] = __builtin_amdgcn_mfma_f32_16x16x32_bf16(af[mf], bfr[nf], acc[mf][nf], 0, 0, 0);
    __syncthreads();
  }
  // C/D layout: col = lane&15, row = (lane>>4)*4 + reg   [m89-verified]
#pragma unroll
  for (int mf = 0; mf < 4; mf++) {
#pragma unroll
    for (int j = 0; j < 4; j++) {
      int r = tm + wm + mf * 16 + q * 4 + j;
      if (r < M) {
#pragma unroll
        for (int nf = 0; nf < 4; nf++) {
          int c = tn + wn + nf * 16 + l;
          float val = acc[mf][nf][j];
          if (bias) val += bf2f(bias[c]);
          Cb[(size_t)r * NC + c] = f2bf(val);
        }
      }
    }
  }
}

// ---------------- fused attention + aggregation, one block per dst node ----------------
#define CHUNK 64
__global__ __launch_bounds__(256)
void attn_kernel(const ushort_t* __restrict__ q, const ushort_t* __restrict__ k,
                 const ushort_t* __restrict__ v, const int* __restrict__ offs,
                 const int* __restrict__ srcS, ushort_t* __restrict__ h, int dout, int Nn) {
  int n = blockIdx.x;
  int tid = threadIdx.x;
  int lane = tid & 63, wave = tid >> 6;
  __shared__ float qs[256];
  __shared__ float wv[CHUNK];
  __shared__ int sv[CHUNK];
  __shared__ float ssum;
  qs[tid] = bf2f(q[(size_t)n * 256 + tid]);
  if (tid == 0) ssum = 0.f;
  int e0 = offs[n], e1 = offs[n + 1];
  float acc = 0.f;
  __syncthreads();
  float q0 = qs[lane * 4 + 0], q1 = qs[lane * 4 + 1];
  float q2 = qs[lane * 4 + 2], q3 = qs[lane * 4 + 3];
  for (int cs = e0; cs < e1; cs += CHUNK) {
    int cnt = min(CHUNK, e1 - cs);
    for (int j = wave; j < cnt; j += 4) {
      int s = srcS[cs + j];
      if (s < 0) s = 0; if (s >= Nn) s = Nn - 1;
      const ushort_t* kr = k + (size_t)s * 256 + lane * 4;
      ushort4 kk = *(const ushort4*)kr;
      float p = q0 * bf2f(kk.x) + q1 * bf2f(kk.y) + q2 * bf2f(kk.z) + q3 * bf2f(kk.w);
#pragma unroll
      for (int o = 32; o > 0; o >>= 1) p += __shfl_xor(p, o);
      if (lane == 0) { wv[j] = __expf(p * 0.0625f); sv[j] = s; }
    }
    __syncthreads();
    if (tid < dout) {
      const ushort_t* vbp = v + tid;
      for (int j = 0; j < cnt; j++)
        acc += wv[j] * bf2f(vbp[(size_t)sv[j] * dout]);
    }
    if (tid == 0) { float s2 = 0.f; for (int j = 0; j < cnt; j++) s2 += wv[j]; ssum += s2; }
    __syncthreads();
  }
  if (tid < dout) {
    size_t idx = (size_t)n * dout + tid;
    float hv = bf2f(h[idx]);  // h already holds x@Wr + b
    h[idx] = f2bf(hv + acc / fmaxf(ssum, 1e-16f));
  }
}

// ---------------- BatchNorm ----------------
__global__ void bn_stats_kernel(const ushort_t* __restrict__ h, float* __restrict__ sum,
                                float* __restrict__ sumsq, int N, int F) {
  int col = threadIdx.x;
  float s = 0.f, s2 = 0.f;
  for (int r = blockIdx.x; r < N; r += gridDim.x) {
    float x = bf2f(h[(size_t)r * F + col]);
    s += x; s2 += x * x;
  }
  atomicAdd(&sum[col], s);
  atomicAdd(&sumsq[col], s2);
}

__global__ void bn_final_kernel(const float* __restrict__ sum, const float* __restrict__ sumsq,
                                const ushort_t* __restrict__ g, const ushort_t* __restrict__ be,
                                float* __restrict__ scale, float* __restrict__ shift, int N, int F) {
  int t = threadIdx.x;
  if (t < F) {
    float mu = sum[t] / (float)N;
    float var = sumsq[t] / (float)N - mu * mu;
    float sc = bf2f(g[t]) * rsqrtf(var + 1e-5f);
    scale[t] = sc;
    shift[t] = bf2f(be[t]) - mu * sc;
  }
}

__global__ void norm_relu_kernel(const ushort_t* __restrict__ h, const float* __restrict__ scale,
                                 const float* __restrict__ shift, ushort_t* __restrict__ x1,
                                 size_t total, int cmask) {
  for (size_t i = blockIdx.x * (size_t)blockDim.x + threadIdx.x; i < total;
       i += (size_t)gridDim.x * blockDim.x) {
    int c = (int)(i & (size_t)cmask);
    float vv = bf2f(h[i]) * scale[c] + shift[c];
    x1[i] = f2bf(relu_nanprop(vv));
  }
}

__global__ void final_kernel(const ushort_t* __restrict__ h, const float* __restrict__ scale,
                             const float* __restrict__ shift, const ushort_t* __restrict__ x0b,
                             void* __restrict__ out, const int* __restrict__ flagF, size_t total) {
  int f = flagF[0];
  for (size_t i = blockIdx.x * (size_t)blockDim.x + threadIdx.x; i < total;
       i += (size_t)gridDim.x * blockDim.x) {
    int c = (int)(i & 127);
    float vv = bf2f(h[i]) * scale[c] + shift[c] + bf2f(x0b[i]);
    vv = relu_nanprop(vv);
    if (f) ((float*)out)[i] = vv;
    else   ((ushort_t*)out)[i] = f2bf(vv);
  }
}

extern "C" void kernel_launch(void* const* d_in, const int* in_sizes, int n_in,
                              void* d_out, int out_size, void* d_ws, size_t ws_size,
                              hipStream_t stream) {
  const void* x0  = d_in[0];
  const void* edges = d_in[1];
  const void* Wq1 = d_in[2];
  const void* Wk1 = d_in[3];
  const void* Wv1 = d_in[4];
  const void* Wr1 = d_in[5];
  const void* b1  = d_in[6];
  const void* gw1 = d_in[7];
  const void* bw1 = d_in[8];
  const void* Wq2 = d_in[9];
  const void* Wk2 = d_in[10];
  const void* Wv2 = d_in[11];
  const void* Wr2 = d_in[12];
  const void* b2  = d_in[13];
  const void* gw2 = d_in[14];
  const void* bw2 = d_in[15];

  int N = in_sizes[0] / 128;
  int E = in_sizes[1] / 2;

  uintptr_t base = (uintptr_t)d_ws;
  auto carve = [&](size_t bytes) -> void* {
    uintptr_t p = base;
    base += (bytes + 255) & ~(size_t)255;
    return (void*)p;
  };
  ushort_t* x0b = (ushort_t*)carve((size_t)N * 128 * 2);
  ushort_t* qb = (ushort_t*)carve((size_t)N * 256 * 2);
  ushort_t* kb = (ushort_t*)carve((size_t)N * 256 * 2);
  ushort_t* vb = (ushort_t*)carve((size_t)N * 256 * 2);
  ushort_t* hb = (ushort_t*)carve((size_t)N * 256 * 2);
  ushort_t* x1 = (ushort_t*)carve((size_t)N * 256 * 2);
  ushort_t* wq1t = (ushort_t*)carve(128 * 256 * 2);
  ushort_t* wk1t = (ushort_t*)carve(128 * 256 * 2);
  ushort_t* wv1t = (ushort_t*)carve(128 * 256 * 2);
  ushort_t* wr1t = (ushort_t*)carve(128 * 256 * 2);
  ushort_t* wq2t = (ushort_t*)carve(256 * 256 * 2);
  ushort_t* wk2t = (ushort_t*)carve(256 * 256 * 2);
  ushort_t* wv2t = (ushort_t*)carve(256 * 128 * 2);
  ushort_t* wr2t = (ushort_t*)carve(256 * 128 * 2);
  ushort_t* b1b  = (ushort_t*)carve(256 * 2);
  ushort_t* g1b  = (ushort_t*)carve(256 * 2);
  ushort_t* be1b = (ushort_t*)carve(256 * 2);
  ushort_t* b2b  = (ushort_t*)carve(128 * 2);
  ushort_t* g2b  = (ushort_t*)carve(128 * 2);
  ushort_t* be2b = (ushort_t*)carve(128 * 2);
  int* offs = (int*)carve((size_t)(N + 1) * 4);
  int* srcS = (int*)carve((size_t)E * 4);
  int nzero = 2 * N + 64 + 1024;
  int* zreg = (int*)carve((size_t)nzero * 4);
  int* deg   = zreg;
  int* fill  = zreg + N;
  int* eflag = zreg + 2 * N;        // [0]=edge wide, [1]=float32 flag
  float* sum1 = (float*)(zreg + 2 * N + 64);
  float* sq1  = sum1 + 256;
  float* sum2 = sum1 + 512;
  float* sq2  = sum1 + 640;
  float* sc1 = (float*)carve(256 * 4);
  float* sh1 = (float*)carve(256 * 4);
  float* sc2 = (float*)carve(128 * 4);
  float* sh2 = (float*)carve(128 * 4);

  size_t needed = base - (uintptr_t)d_ws;
  if (needed > ws_size) return;  // all-zero-output signature => ws insufficient

  int* fF = eflag + 1;

  zero_kernel<<<256, 256, 0, stream>>>(zreg, nzero);
  detect_kernel<<<1, 256, 0, stream>>>((const int*)edges, eflag, 2 * E);
  detect_f32_kernel<<<1, 256, 0, stream>>>((const unsigned int*)x0, fF, N * 128);

  // convert inputs to bf16 scratch (or copy if already bf16)
  cvt_kernel<<<4096, 256, 0, stream>>>(x0, x0b, N * 128, fF);
  cvt_kernel<<<1, 256, 0, stream>>>(b1, b1b, 256, fF);
  cvt_kernel<<<1, 256, 0, stream>>>(gw1, g1b, 256, fF);
  cvt_kernel<<<1, 256, 0, stream>>>(bw1, be1b, 256, fF);
  cvt_kernel<<<1, 128, 0, stream>>>(b2, b2b, 128, fF);
  cvt_kernel<<<1, 128, 0, stream>>>(gw2, g2b, 128, fF);
  cvt_kernel<<<1, 128, 0, stream>>>(bw2, be2b, 128, fF);
  cvt_transpose_kernel<<<(128 * 256 + 255) / 256, 256, 0, stream>>>(Wq1, wq1t, 128, 256, fF);
  cvt_transpose_kernel<<<(128 * 256 + 255) / 256, 256, 0, stream>>>(Wk1, wk1t, 128, 256, fF);
  cvt_transpose_kernel<<<(128 * 256 + 255) / 256, 256, 0, stream>>>(Wv1, wv1t, 128, 256, fF);
  cvt_transpose_kernel<<<(128 * 256 + 255) / 256, 256, 0, stream>>>(Wr1, wr1t, 128, 256, fF);
  cvt_transpose_kernel<<<(256 * 256 + 255) / 256, 256, 0, stream>>>(Wq2, wq2t, 256, 256, fF);
  cvt_transpose_kernel<<<(256 * 256 + 255) / 256, 256, 0, stream>>>(Wk2, wk2t, 256, 256, fF);
  cvt_transpose_kernel<<<(256 * 128 + 255) / 256, 256, 0, stream>>>(Wv2, wv2t, 256, 128, fF);
  cvt_transpose_kernel<<<(256 * 128 + 255) / 256, 256, 0, stream>>>(Wr2, wr2t, 256, 128, fF);

  hist_kernel<<<1024, 256, 0, stream>>>(edges, eflag, deg, E, N);
  scan_kernel<<<1, 256, 0, stream>>>(deg, offs, N);
  scatter_kernel<<<1024, 256, 0, stream>>>(edges, eflag, offs, fill, srcS, E, N);

  dim3 gA((N + 127) / 128, 2);
  dim3 gB((N + 127) / 128, 1);
  // Layer 1
  gemm_kernel<<<gA, 256, 0, stream>>>(x0b, wq1t, qb, nullptr, N, 128, 256);
  gemm_kernel<<<gA, 256, 0, stream>>>(x0b, wk1t, kb, nullptr, N, 128, 256);
  gemm_kernel<<<gA, 256, 0, stream>>>(x0b, wv1t, vb, nullptr, N, 128, 256);
  gemm_kernel<<<gA, 256, 0, stream>>>(x0b, wr1t, hb, b1b, N, 128, 256);
  attn_kernel<<<N, 256, 0, stream>>>(qb, kb, vb, offs, srcS, hb, 256, N);
  bn_stats_kernel<<<512, 256, 0, stream>>>(hb, sum1, sq1, N, 256);
  bn_final_kernel<<<1, 256, 0, stream>>>(sum1, sq1, g1b, be1b, sc1, sh1, N, 256);
  norm_relu_kernel<<<4096, 256, 0, stream>>>(hb, sc1, sh1, x1, (size_t)N * 256, 255);
  // Layer 2
  gemm_kernel<<<gA, 256, 0, stream>>>(x1, wq2t, qb, nullptr, N, 256, 256);
  gemm_kernel<<<gA, 256, 0, stream>>>(x1, wk2t, kb, nullptr, N, 256, 256);
  gemm_kernel<<<gB, 256, 0, stream>>>(x1, wv2t, vb, nullptr, N, 256, 128);
  gemm_kernel<<<gB, 256, 0, stream>>>(x1, wr2t, hb, b2b, N, 256, 128);
  attn_kernel<<<N, 256, 0, stream>>>(qb, kb, vb, offs, srcS, hb, 128, N);
  bn_stats_kernel<<<512, 128, 0, stream>>>(hb, sum2, sq2, N, 128);
  bn_final_kernel<<<1, 128, 0, stream>>>(sum2, sq2, g2b, be2b, sc2, sh2, N, 128);
  final_kernel<<<4096, 256, 0, stream>>>(hb, sc2, sh2, x0b, d_out, fF, (size_t)N * 128);
}

// Round 5
// 840.136 us; speedup vs baseline: 1.3011x; 1.3011x over previous
//
#include <hip/hip_runtime.h>
#include <stdint.h>

typedef unsigned short ushort_t;

__device__ __forceinline__ float bf2f(unsigned short u) {
  union { unsigned int i; float f; } c; c.i = ((unsigned int)u) << 16; return c.f;
}
__device__ __forceinline__ unsigned short f2bf(float f) {
  union { float f; unsigned int i; } c; c.f = f;
  unsigned int r = c.i + 0x7FFFu + ((c.i >> 16) & 1u);
  return (unsigned short)(r >> 16);
}
// NaN-propagating relu (tripwire: NaN stays visible)
__device__ __forceinline__ float relu_nanprop(float v) { return (v < 0.f) ? 0.f : v; }

typedef __attribute__((ext_vector_type(8))) short s16x8;
typedef __attribute__((ext_vector_type(4))) float f32x4;

// ---------------- zero scratch ints ----------------
__global__ void zero_kernel(int* __restrict__ p, int n) {
  for (int i = blockIdx.x * blockDim.x + threadIdx.x; i < n; i += gridDim.x * blockDim.x)
    p[i] = 0;
}

// ---------------- float32-vs-bf16 detection on x0 ----------------
__global__ void detect_f32_kernel(const unsigned int* __restrict__ x, int* __restrict__ flagF, int nw) {
  __shared__ int cnt;
  if (threadIdx.x == 0) cnt = 0;
  __syncthreads();
  int local = 0;
  for (int i = threadIdx.x; i < 4096 && i < nw; i += blockDim.x) {
    unsigned int low = x[i] & 0xFFFFu;
    unsigned int e = (low >> 7) & 0xFFu;
    if (low != 0u && (e < 96u || e > 144u)) local++;
  }
  atomicAdd(&cnt, local);
  __syncthreads();
  if (threadIdx.x == 0) flagF[0] = (cnt > 1024) ? 1 : 0;  // 1 => float32 inputs
}

// ---------------- edge dtype detection (int64 vs int32) ----------------
__global__ void detect_kernel(const int* __restrict__ e32, int* __restrict__ flag, int n32) {
  __shared__ int any;
  if (threadIdx.x == 0) any = 0;
  __syncthreads();
  for (int i = threadIdx.x; i < 4096; i += blockDim.x) {
    int idx = 2 * i + 1;
    if (idx < n32 && e32[idx] != 0) any = 1;
  }
  __syncthreads();
  if (threadIdx.x == 0) flag[0] = (any == 0) ? 1 : 0;  // 1 => int64
}

__device__ __forceinline__ int edge_at(const void* edges, int wide, int idx) {
  if (wide) return (int)((const long long*)edges)[idx];
  return ((const int*)edges)[idx];
}

// ---------------- convert input (float32 or bf16) -> bf16 ----------------
__global__ void cvt_kernel(const void* __restrict__ in, ushort_t* __restrict__ out,
                           int n, const int* __restrict__ flagF) {
  int f = flagF[0];
  for (int i = blockIdx.x * blockDim.x + threadIdx.x; i < n; i += gridDim.x * blockDim.x)
    out[i] = f ? f2bf(((const float*)in)[i]) : ((const ushort_t*)in)[i];
}

// 6 small param vectors in one launch
__global__ void cvt_params_kernel(const void* p0, const void* p1, const void* p2,
                                  const void* p3, const void* p4, const void* p5,
                                  ushort_t* o0, ushort_t* o1, ushort_t* o2,
                                  ushort_t* o3, ushort_t* o4, ushort_t* o5,
                                  int n0, int n3, const int* __restrict__ flagF) {
  int f = flagF[0];
  int t = blockIdx.x * blockDim.x + threadIdx.x;
  const void* ins[6] = {p0, p1, p2, p3, p4, p5};
  ushort_t* outs[6] = {o0, o1, o2, o3, o4, o5};
  int sizes[6] = {n0, n0, n0, n3, n3, n3};
  int off = 0;
  for (int s = 0; s < 6; s++) {
    int i = t - off;
    if (i >= 0 && i < sizes[s])
      outs[s][i] = f ? f2bf(((const float*)ins[s])[i]) : ((const ushort_t*)ins[s])[i];
    off += sizes[s];
  }
}

// ---------------- convert + transpose 4 weights into one cat buffer ----------------
// W0,W1: [K][C01], W2,W3: [K][C23]. out row r (length K): col c of the cat matrix.
__global__ void cvt_transpose4_kernel(const void* W0, const void* W1, const void* W2, const void* W3,
                                      ushort_t* __restrict__ out, int K, int C01, int C23,
                                      const int* __restrict__ flagF) {
  int f = flagF[0];
  int per01 = K * C01, per23 = K * C23;
  int total = 2 * per01 + 2 * per23;
  for (int i = blockIdx.x * blockDim.x + threadIdx.x; i < total; i += gridDim.x * blockDim.x) {
    const void* W; int rem, C, rowoff;
    if (i < per01)                { W = W0; rem = i;                 C = C01; rowoff = 0; }
    else if (i < 2 * per01)       { W = W1; rem = i - per01;         C = C01; rowoff = C01; }
    else if (i < 2 * per01 + per23){ W = W2; rem = i - 2 * per01;    C = C23; rowoff = 2 * C01; }
    else                          { W = W3; rem = i - 2 * per01 - per23; C = C23; rowoff = 2 * C01 + C23; }
    int k = rem / C, c = rem - k * C;
    ushort_t v = f ? f2bf(((const float*)W)[rem]) : ((const ushort_t*)W)[rem];
    out[(size_t)(rowoff + c) * K + k] = v;
  }
}

// ---------------- CSR build ----------------
__global__ void hist_kernel(const void* __restrict__ edges, const int* __restrict__ flag,
                            int* __restrict__ deg, int E, int Nn) {
  int wide = flag[0];
  for (int e = blockIdx.x * blockDim.x + threadIdx.x; e < E; e += gridDim.x * blockDim.x) {
    int d = edge_at(edges, wide, E + e);
    if (d < 0) d = 0; if (d >= Nn) d = Nn - 1;
    atomicAdd(&deg[d], 1);
  }
}

// 3-phase parallel scan (chunk = 256): supports N <= 65536
__global__ void chunk_sum_kernel(const int* __restrict__ deg, int* __restrict__ csum, int n) {
  int b = blockIdx.x, t = threadIdx.x, i = b * 256 + t;
  int v = (i < n) ? deg[i] : 0;
  __shared__ int ws[4];
#pragma unroll
  for (int o = 32; o > 0; o >>= 1) v += __shfl_down(v, o);
  if ((t & 63) == 0) ws[t >> 6] = v;
  __syncthreads();
  if (t == 0) csum[b] = ws[0] + ws[1] + ws[2] + ws[3];
}

__global__ void scan_small_kernel(const int* __restrict__ csum, int* __restrict__ cpre,
                                  int nc, int* __restrict__ offs, int N) {
  __shared__ int tmp[256];
  int t = threadIdx.x;
  int v = (t < nc) ? csum[t] : 0;
  tmp[t] = v;
  __syncthreads();
  for (int off = 1; off < 256; off <<= 1) {
    int x = (t >= off) ? tmp[t - off] : 0;
    __syncthreads();
    tmp[t] += x;
    __syncthreads();
  }
  if (t < nc) cpre[t] = tmp[t] - v;
  if (t == 255) offs[N] = tmp[255];
}

__global__ void scan_final_kernel(const int* __restrict__ deg, const int* __restrict__ cpre,
                                  int* __restrict__ offs, int n) {
  int b = blockIdx.x, t = threadIdx.x, i = b * 256 + t;
  __shared__ int tmp[256];
  int v = (i < n) ? deg[i] : 0;
  tmp[t] = v;
  __syncthreads();
  for (int off = 1; off < 256; off <<= 1) {
    int x = (t >= off) ? tmp[t - off] : 0;
    __syncthreads();
    tmp[t] += x;
    __syncthreads();
  }
  if (i < n) offs[i] = cpre[b] + tmp[t] - v;
}

__global__ void scatter_kernel(const void* __restrict__ edges, const int* __restrict__ flag,
                               const int* __restrict__ offs, int* __restrict__ fill,
                               int* __restrict__ srcS, int E, int Nn) {
  int wide = flag[0];
  for (int e = blockIdx.x * blockDim.x + threadIdx.x; e < E; e += gridDim.x * blockDim.x) {
    int s = edge_at(edges, wide, e);
    int d = edge_at(edges, wide, E + e);
    if (d < 0) d = 0; if (d >= Nn) d = Nn - 1;
    if (s < 0) s = 0; if (s >= Nn) s = Nn - 1;
    int p = offs[d] + atomicAdd(&fill[d], 1);
    if (p < 0) p = 0; if (p >= E) p = E - 1;
    srcS[p] = s;
  }
}

// ---------------- fused 4-way GEMM: [q|k|v|h] = A @ Wcat, bf16 in/out ----------------
// BT rows are columns of the cat matrix. Sections: [0,b0) q, [b0,b1) k, [b1,b2) v, [b2,NC) h(+bias).
__global__ __launch_bounds__(256)
void gemm4_kernel(const ushort_t* __restrict__ A, const ushort_t* __restrict__ BT,
                  ushort_t* __restrict__ o0, ushort_t* __restrict__ o1,
                  ushort_t* __restrict__ o2, ushort_t* __restrict__ o3,
                  const ushort_t* __restrict__ bias3,
                  int M, int K, int NC, int b0, int b1, int b2) {
  __shared__ __align__(16) ushort_t As[128 * 32];
  __shared__ __align__(16) ushort_t Bs[128 * 32];
  int tid = threadIdx.x;
  int lane = tid & 63, wave = tid >> 6;
  int tm = blockIdx.x * 128, tn = blockIdx.y * 128;
  int wm = (wave >> 1) * 64, wn = (wave & 1) * 64;
  int q = lane >> 4, l = lane & 15;
  f32x4 acc[4][4];
#pragma unroll
  for (int a = 0; a < 4; a++)
#pragma unroll
    for (int b = 0; b < 4; b++) acc[a][b] = (f32x4){0.f, 0.f, 0.f, 0.f};

  for (int k0 = 0; k0 < K; k0 += 32) {
#pragma unroll
    for (int t = 0; t < 2; t++) {
      int u = t * 256 + tid;
      int row = u >> 2, c8 = (u & 3) * 8;
      int ra = tm + row; if (ra > M - 1) ra = M - 1;
      *(uint4*)&As[row * 32 + c8] = *(const uint4*)&A[(size_t)ra * K + k0 + c8];
      *(uint4*)&Bs[row * 32 + c8] = *(const uint4*)&BT[(size_t)(tn + row) * K + k0 + c8];
    }
    __syncthreads();
    s16x8 af[4], bfr[4];
#pragma unroll
    for (int mf = 0; mf < 4; mf++) af[mf] = *(const s16x8*)&As[(wm + mf * 16 + l) * 32 + q * 8];
#pragma unroll
    for (int nf = 0; nf < 4; nf++) bfr[nf] = *(const s16x8*)&Bs[(wn + nf * 16 + l) * 32 + q * 8];
#pragma unroll
    for (int mf = 0; mf < 4; mf++)
#pragma unroll
      for (int nf = 0; nf < 4; nf++)
        acc[mf][nf] = __builtin_amdgcn_mfma_f32_16x16x32_bf16(af[mf], bfr[nf], acc[mf][nf], 0, 0, 0);
    __syncthreads();
  }
  // C/D layout: col = lane&15, row = (lane>>4)*4 + reg   [m89-verified]
#pragma unroll
  for (int mf = 0; mf < 4; mf++) {
#pragma unroll
    for (int j = 0; j < 4; j++) {
      int r = tm + wm + mf * 16 + q * 4 + j;
      if (r < M) {
#pragma unroll
        for (int nf = 0; nf < 4; nf++) {
          int c = tn + wn + nf * 16 + l;
          float val = acc[mf][nf][j];
          ushort_t* op; int lc, w;
          if (c < b0)      { op = o0; lc = c;      w = b0; }
          else if (c < b1) { op = o1; lc = c - b0; w = b1 - b0; }
          else if (c < b2) { op = o2; lc = c - b1; w = b2 - b1; }
          else             { op = o3; lc = c - b2; w = NC - b2; val += bf2f(bias3[lc]); }
          op[(size_t)r * w + lc] = f2bf(val);
        }
      }
    }
  }
}

// ---------------- fused attention + aggregation, one block per dst node ----------------
#define CHUNK 64
__global__ __launch_bounds__(256)
void attn_kernel(const ushort_t* __restrict__ q, const ushort_t* __restrict__ k,
                 const ushort_t* __restrict__ v, const int* __restrict__ offs,
                 const int* __restrict__ srcS, ushort_t* __restrict__ h, int dout, int Nn) {
  int n = blockIdx.x;
  int tid = threadIdx.x;
  int lane = tid & 63, wave = tid >> 6;
  __shared__ float qs[256];
  __shared__ float wv[CHUNK];
  __shared__ int sv[CHUNK];
  __shared__ float ssum;
  qs[tid] = bf2f(q[(size_t)n * 256 + tid]);
  if (tid == 0) ssum = 0.f;
  int e0 = offs[n], e1 = offs[n + 1];
  float acc = 0.f;
  __syncthreads();
  float q0 = qs[lane * 4 + 0], q1 = qs[lane * 4 + 1];
  float q2 = qs[lane * 4 + 2], q3 = qs[lane * 4 + 3];
  for (int cs = e0; cs < e1; cs += CHUNK) {
    int cnt = min(CHUNK, e1 - cs);
    for (int j = wave; j < cnt; j += 4) {
      int s = srcS[cs + j];
      if (s < 0) s = 0; if (s >= Nn) s = Nn - 1;
      const ushort_t* kr = k + (size_t)s * 256 + lane * 4;
      ushort4 kk = *(const ushort4*)kr;
      float p = q0 * bf2f(kk.x) + q1 * bf2f(kk.y) + q2 * bf2f(kk.z) + q3 * bf2f(kk.w);
#pragma unroll
      for (int o = 32; o > 0; o >>= 1) p += __shfl_xor(p, o);
      if (lane == 0) { wv[j] = __expf(p * 0.0625f); sv[j] = s; }
    }
    __syncthreads();
    if (tid < dout) {
      const ushort_t* vbp = v + tid;
      for (int j = 0; j < cnt; j++)
        acc += wv[j] * bf2f(vbp[(size_t)sv[j] * dout]);
    }
    if (tid == 0) { float s2 = 0.f; for (int j = 0; j < cnt; j++) s2 += wv[j]; ssum += s2; }
    __syncthreads();
  }
  if (tid < dout) {
    size_t idx = (size_t)n * dout + tid;
    float hv = bf2f(h[idx]);  // h already holds x@Wr + b
    h[idx] = f2bf(hv + acc / fmaxf(ssum, 1e-16f));
  }
}

// ---------------- BatchNorm ----------------
__global__ void bn_stats_kernel(const ushort_t* __restrict__ h, float* __restrict__ sum,
                                float* __restrict__ sumsq, int N, int F) {
  int col = threadIdx.x;
  float s = 0.f, s2 = 0.f;
  for (int r = blockIdx.x; r < N; r += gridDim.x) {
    float x = bf2f(h[(size_t)r * F + col]);
    s += x; s2 += x * x;
  }
  atomicAdd(&sum[col], s);
  atomicAdd(&sumsq[col], s2);
}

__global__ void bn_final_kernel(const float* __restrict__ sum, const float* __restrict__ sumsq,
                                const ushort_t* __restrict__ g, const ushort_t* __restrict__ be,
                                float* __restrict__ scale, float* __restrict__ shift, int N, int F) {
  int t = threadIdx.x;
  if (t < F) {
    float mu = sum[t] / (float)N;
    float var = sumsq[t] / (float)N - mu * mu;
    float sc = bf2f(g[t]) * rsqrtf(var + 1e-5f);
    scale[t] = sc;
    shift[t] = bf2f(be[t]) - mu * sc;
  }
}

__global__ void norm_relu_kernel(const ushort_t* __restrict__ h, const float* __restrict__ scale,
                                 const float* __restrict__ shift, ushort_t* __restrict__ x1,
                                 size_t total, int cmask) {
  for (size_t i = blockIdx.x * (size_t)blockDim.x + threadIdx.x; i < total;
       i += (size_t)gridDim.x * blockDim.x) {
    int c = (int)(i & (size_t)cmask);
    float vv = bf2f(h[i]) * scale[c] + shift[c];
    x1[i] = f2bf(relu_nanprop(vv));
  }
}

__global__ void final_kernel(const ushort_t* __restrict__ h, const float* __restrict__ scale,
                             const float* __restrict__ shift, const ushort_t* __restrict__ x0b,
                             void* __restrict__ out, const int* __restrict__ flagF, size_t total) {
  int f = flagF[0];
  for (size_t i = blockIdx.x * (size_t)blockDim.x + threadIdx.x; i < total;
       i += (size_t)gridDim.x * blockDim.x) {
    int c = (int)(i & 127);
    float vv = bf2f(h[i]) * scale[c] + shift[c] + bf2f(x0b[i]);
    vv = relu_nanprop(vv);
    if (f) ((float*)out)[i] = vv;
    else   ((ushort_t*)out)[i] = f2bf(vv);
  }
}

extern "C" void kernel_launch(void* const* d_in, const int* in_sizes, int n_in,
                              void* d_out, int out_size, void* d_ws, size_t ws_size,
                              hipStream_t stream) {
  const void* x0  = d_in[0];
  const void* edges = d_in[1];
  const void* Wq1 = d_in[2];
  const void* Wk1 = d_in[3];
  const void* Wv1 = d_in[4];
  const void* Wr1 = d_in[5];
  const void* b1  = d_in[6];
  const void* gw1 = d_in[7];
  const void* bw1 = d_in[8];
  const void* Wq2 = d_in[9];
  const void* Wk2 = d_in[10];
  const void* Wv2 = d_in[11];
  const void* Wr2 = d_in[12];
  const void* b2  = d_in[13];
  const void* gw2 = d_in[14];
  const void* bw2 = d_in[15];

  int N = in_sizes[0] / 128;
  int E = in_sizes[1] / 2;
  int NCHUNK = (N + 255) / 256;

  uintptr_t base = (uintptr_t)d_ws;
  auto carve = [&](size_t bytes) -> void* {
    uintptr_t p = base;
    base += (bytes + 255) & ~(size_t)255;
    return (void*)p;
  };
  ushort_t* x0b = (ushort_t*)carve((size_t)N * 128 * 2);
  ushort_t* qb = (ushort_t*)carve((size_t)N * 256 * 2);
  ushort_t* kb = (ushort_t*)carve((size_t)N * 256 * 2);
  ushort_t* vb = (ushort_t*)carve((size_t)N * 256 * 2);
  ushort_t* hb = (ushort_t*)carve((size_t)N * 256 * 2);
  ushort_t* x1 = (ushort_t*)carve((size_t)N * 256 * 2);
  ushort_t* wcat1 = (ushort_t*)carve((size_t)1024 * 128 * 2);  // 4x [128->256] transposed
  ushort_t* wcat2 = (ushort_t*)carve((size_t)768 * 256 * 2);   // 2x [256->256] + 2x [256->128]
  ushort_t* b1b  = (ushort_t*)carve(256 * 2);
  ushort_t* g1b  = (ushort_t*)carve(256 * 2);
  ushort_t* be1b = (ushort_t*)carve(256 * 2);
  ushort_t* b2b  = (ushort_t*)carve(128 * 2);
  ushort_t* g2b  = (ushort_t*)carve(128 * 2);
  ushort_t* be2b = (ushort_t*)carve(128 * 2);
  int* offs = (int*)carve((size_t)(N + 1) * 4);
  int* srcS = (int*)carve((size_t)E * 4);
  int* csum = (int*)carve(256 * 4);
  int* cpre = (int*)carve(256 * 4);
  int nzero = 2 * N + 64 + 1024;
  int* zreg = (int*)carve((size_t)nzero * 4);
  int* deg   = zreg;
  int* fill  = zreg + N;
  int* eflag = zreg + 2 * N;        // [0]=edge wide, [1]=float32 flag
  float* sum1 = (float*)(zreg + 2 * N + 64);
  float* sq1  = sum1 + 256;
  float* sum2 = sum1 + 512;
  float* sq2  = sum1 + 640;
  float* sc1 = (float*)carve(256 * 4);
  float* sh1 = (float*)carve(256 * 4);
  float* sc2 = (float*)carve(128 * 4);
  float* sh2 = (float*)carve(128 * 4);

  size_t needed = base - (uintptr_t)d_ws;
  if (needed > ws_size) return;

  int* fF = eflag + 1;

  zero_kernel<<<256, 256, 0, stream>>>(zreg, nzero);
  detect_kernel<<<1, 256, 0, stream>>>((const int*)edges, eflag, 2 * E);
  detect_f32_kernel<<<1, 256, 0, stream>>>((const unsigned int*)x0, fF, N * 128);

  cvt_kernel<<<4096, 256, 0, stream>>>(x0, x0b, N * 128, fF);
  cvt_params_kernel<<<5, 256, 0, stream>>>(b1, gw1, bw1, b2, gw2, bw2,
                                           b1b, g1b, be1b, b2b, g2b, be2b, 256, 128, fF);
  cvt_transpose4_kernel<<<512, 256, 0, stream>>>(Wq1, Wk1, Wv1, Wr1, wcat1, 128, 256, 256, fF);
  cvt_transpose4_kernel<<<512, 256, 0, stream>>>(Wq2, Wk2, Wv2, Wr2, wcat2, 256, 256, 128, fF);

  hist_kernel<<<1024, 256, 0, stream>>>(edges, eflag, deg, E, N);
  chunk_sum_kernel<<<NCHUNK, 256, 0, stream>>>(deg, csum, N);
  scan_small_kernel<<<1, 256, 0, stream>>>(csum, cpre, NCHUNK, offs, N);
  scan_final_kernel<<<NCHUNK, 256, 0, stream>>>(deg, cpre, offs, N);
  scatter_kernel<<<1024, 256, 0, stream>>>(edges, eflag, offs, fill, srcS, E, N);

  dim3 gA1((N + 127) / 128, 8);   // NC=1024
  dim3 gA2((N + 127) / 128, 6);   // NC=768
  // Layer 1: fused q|k|v|h GEMM
  gemm4_kernel<<<gA1, 256, 0, stream>>>(x0b, wcat1, qb, kb, vb, hb, b1b,
                                        N, 128, 1024, 256, 512, 768);
  attn_kernel<<<N, 256, 0, stream>>>(qb, kb, vb, offs, srcS, hb, 256, N);
  bn_stats_kernel<<<512, 256, 0, stream>>>(hb, sum1, sq1, N, 256);
  bn_final_kernel<<<1, 256, 0, stream>>>(sum1, sq1, g1b, be1b, sc1, sh1, N, 256);
  norm_relu_kernel<<<4096, 256, 0, stream>>>(hb, sc1, sh1, x1, (size_t)N * 256, 255);
  // Layer 2
  gemm4_kernel<<<gA2, 256, 0, stream>>>(x1, wcat2, qb, kb, vb, hb, b2b,
                                        N, 256, 768, 256, 512, 640);
  attn_kernel<<<N, 256, 0, stream>>>(qb, kb, vb, offs, srcS, hb, 128, N);
  bn_stats_kernel<<<512, 128, 0, stream>>>(hb, sum2, sq2, N, 128);
  bn_final_kernel<<<1, 128, 0, stream>>>(sum2, sq2, g2b, be2b, sc2, sh2, N, 128);
  final_kernel<<<4096, 256, 0, stream>>>(hb, sc2, sh2, x0b, d_out, fF, (size_t)N * 128);
}

// Round 6
// 812.758 us; speedup vs baseline: 1.3449x; 1.0337x over previous
//
#include <hip/hip_runtime.h>
#include <stdint.h>

typedef unsigned short ushort_t;

__device__ __forceinline__ float bf2f(unsigned short u) {
  union { unsigned int i; float f; } c; c.i = ((unsigned int)u) << 16; return c.f;
}
__device__ __forceinline__ unsigned short f2bf(float f) {
  union { float f; unsigned int i; } c; c.f = f;
  unsigned int r = c.i + 0x7FFFu + ((c.i >> 16) & 1u);
  return (unsigned short)(r >> 16);
}
// NaN-propagating relu (tripwire: NaN stays visible)
__device__ __forceinline__ float relu_nanprop(float v) { return (v < 0.f) ? 0.f : v; }

typedef __attribute__((ext_vector_type(8))) short s16x8;
typedef __attribute__((ext_vector_type(4))) float f32x4;

// ---------------- zero scratch ints ----------------
__global__ void zero_kernel(int* __restrict__ p, int n) {
  for (int i = blockIdx.x * blockDim.x + threadIdx.x; i < n; i += gridDim.x * blockDim.x)
    p[i] = 0;
}

// ---------------- float32-vs-bf16 detection on x0 ----------------
__global__ void detect_f32_kernel(const unsigned int* __restrict__ x, int* __restrict__ flagF, int nw) {
  __shared__ int cnt;
  if (threadIdx.x == 0) cnt = 0;
  __syncthreads();
  int local = 0;
  for (int i = threadIdx.x; i < 4096 && i < nw; i += blockDim.x) {
    unsigned int low = x[i] & 0xFFFFu;
    unsigned int e = (low >> 7) & 0xFFu;
    if (low != 0u && (e < 96u || e > 144u)) local++;
  }
  atomicAdd(&cnt, local);
  __syncthreads();
  if (threadIdx.x == 0) flagF[0] = (cnt > 1024) ? 1 : 0;  // 1 => float32 inputs
}

// ---------------- edge dtype detection (int64 vs int32) ----------------
__global__ void detect_kernel(const int* __restrict__ e32, int* __restrict__ flag, int n32) {
  __shared__ int any;
  if (threadIdx.x == 0) any = 0;
  __syncthreads();
  for (int i = threadIdx.x; i < 4096; i += blockDim.x) {
    int idx = 2 * i + 1;
    if (idx < n32 && e32[idx] != 0) any = 1;
  }
  __syncthreads();
  if (threadIdx.x == 0) flag[0] = (any == 0) ? 1 : 0;  // 1 => int64
}

__device__ __forceinline__ int edge_at(const void* edges, int wide, int idx) {
  if (wide) return (int)((const long long*)edges)[idx];
  return ((const int*)edges)[idx];
}

// ---------------- convert input (float32 or bf16) -> bf16 ----------------
__global__ void cvt_kernel(const void* __restrict__ in, ushort_t* __restrict__ out,
                           int n, const int* __restrict__ flagF) {
  int f = flagF[0];
  for (int i = blockIdx.x * blockDim.x + threadIdx.x; i < n; i += gridDim.x * blockDim.x)
    out[i] = f ? f2bf(((const float*)in)[i]) : ((const ushort_t*)in)[i];
}

// 6 small param vectors in one launch
__global__ void cvt_params_kernel(const void* p0, const void* p1, const void* p2,
                                  const void* p3, const void* p4, const void* p5,
                                  ushort_t* o0, ushort_t* o1, ushort_t* o2,
                                  ushort_t* o3, ushort_t* o4, ushort_t* o5,
                                  int n0, int n3, const int* __restrict__ flagF) {
  int f = flagF[0];
  int t = blockIdx.x * blockDim.x + threadIdx.x;
  const void* ins[6] = {p0, p1, p2, p3, p4, p5};
  ushort_t* outs[6] = {o0, o1, o2, o3, o4, o5};
  int sizes[6] = {n0, n0, n0, n3, n3, n3};
  int off = 0;
  for (int s = 0; s < 6; s++) {
    int i = t - off;
    if (i >= 0 && i < sizes[s])
      outs[s][i] = f ? f2bf(((const float*)ins[s])[i]) : ((const ushort_t*)ins[s])[i];
    off += sizes[s];
  }
}

// ---------------- convert + transpose 4 weights into one cat buffer ----------------
__global__ void cvt_transpose4_kernel(const void* W0, const void* W1, const void* W2, const void* W3,
                                      ushort_t* __restrict__ out, int K, int C01, int C23,
                                      const int* __restrict__ flagF) {
  int f = flagF[0];
  int per01 = K * C01, per23 = K * C23;
  int total = 2 * per01 + 2 * per23;
  for (int i = blockIdx.x * blockDim.x + threadIdx.x; i < total; i += gridDim.x * blockDim.x) {
    const void* W; int rem, C, rowoff;
    if (i < per01)                { W = W0; rem = i;                 C = C01; rowoff = 0; }
    else if (i < 2 * per01)       { W = W1; rem = i - per01;         C = C01; rowoff = C01; }
    else if (i < 2 * per01 + per23){ W = W2; rem = i - 2 * per01;    C = C23; rowoff = 2 * C01; }
    else                          { W = W3; rem = i - 2 * per01 - per23; C = C23; rowoff = 2 * C01 + C23; }
    int k = rem / C, c = rem - k * C;
    ushort_t v = f ? f2bf(((const float*)W)[rem]) : ((const ushort_t*)W)[rem];
    out[(size_t)(rowoff + c) * K + k] = v;
  }
}

// ---------------- CSR build ----------------
__global__ void hist_kernel(const void* __restrict__ edges, const int* __restrict__ flag,
                            int* __restrict__ deg, int E, int Nn) {
  int wide = flag[0];
  for (int e = blockIdx.x * blockDim.x + threadIdx.x; e < E; e += gridDim.x * blockDim.x) {
    int d = edge_at(edges, wide, E + e);
    if (d < 0) d = 0; if (d >= Nn) d = Nn - 1;
    atomicAdd(&deg[d], 1);
  }
}

// 3-phase parallel scan (chunk = 256): supports N <= 65536
__global__ void chunk_sum_kernel(const int* __restrict__ deg, int* __restrict__ csum, int n) {
  int b = blockIdx.x, t = threadIdx.x, i = b * 256 + t;
  int v = (i < n) ? deg[i] : 0;
  __shared__ int ws[4];
#pragma unroll
  for (int o = 32; o > 0; o >>= 1) v += __shfl_down(v, o);
  if ((t & 63) == 0) ws[t >> 6] = v;
  __syncthreads();
  if (t == 0) csum[b] = ws[0] + ws[1] + ws[2] + ws[3];
}

__global__ void scan_small_kernel(const int* __restrict__ csum, int* __restrict__ cpre,
                                  int nc, int* __restrict__ offs, int N) {
  __shared__ int tmp[256];
  int t = threadIdx.x;
  int v = (t < nc) ? csum[t] : 0;
  tmp[t] = v;
  __syncthreads();
  for (int off = 1; off < 256; off <<= 1) {
    int x = (t >= off) ? tmp[t - off] : 0;
    __syncthreads();
    tmp[t] += x;
    __syncthreads();
  }
  if (t < nc) cpre[t] = tmp[t] - v;
  if (t == 255) offs[N] = tmp[255];
}

__global__ void scan_final_kernel(const int* __restrict__ deg, const int* __restrict__ cpre,
                                  int* __restrict__ offs, int n) {
  int b = blockIdx.x, t = threadIdx.x, i = b * 256 + t;
  __shared__ int tmp[256];
  int v = (i < n) ? deg[i] : 0;
  tmp[t] = v;
  __syncthreads();
  for (int off = 1; off < 256; off <<= 1) {
    int x = (t >= off) ? tmp[t - off] : 0;
    __syncthreads();
    tmp[t] += x;
    __syncthreads();
  }
  if (i < n) offs[i] = cpre[b] + tmp[t] - v;
}

__global__ void scatter_kernel(const void* __restrict__ edges, const int* __restrict__ flag,
                               const int* __restrict__ offs, int* __restrict__ fill,
                               int* __restrict__ srcS, int E, int Nn) {
  int wide = flag[0];
  for (int e = blockIdx.x * blockDim.x + threadIdx.x; e < E; e += gridDim.x * blockDim.x) {
    int s = edge_at(edges, wide, e);
    int d = edge_at(edges, wide, E + e);
    if (d < 0) d = 0; if (d >= Nn) d = Nn - 1;
    if (s < 0) s = 0; if (s >= Nn) s = Nn - 1;
    int p = offs[d] + atomicAdd(&fill[d], 1);
    if (p < 0) p = 0; if (p >= E) p = E - 1;
    srcS[p] = s;
  }
}

// ---------------- fused 4-way GEMM: [q|k|v|h] = A @ Wcat, bf16 in/out ----------------
__global__ __launch_bounds__(256)
void gemm4_kernel(const ushort_t* __restrict__ A, const ushort_t* __restrict__ BT,
                  ushort_t* __restrict__ o0, ushort_t* __restrict__ o1,
                  ushort_t* __restrict__ o2, ushort_t* __restrict__ o3,
                  const ushort_t* __restrict__ bias3,
                  int M, int K, int NC, int b0, int b1, int b2) {
  __shared__ __align__(16) ushort_t As[128 * 32];
  __shared__ __align__(16) ushort_t Bs[128 * 32];
  int tid = threadIdx.x;
  int lane = tid & 63, wave = tid >> 6;
  int tm = blockIdx.x * 128, tn = blockIdx.y * 128;
  int wm = (wave >> 1) * 64, wn = (wave & 1) * 64;
  int q = lane >> 4, l = lane & 15;
  f32x4 acc[4][4];
#pragma unroll
  for (int a = 0; a < 4; a++)
#pragma unroll
    for (int b = 0; b < 4; b++) acc[a][b] = (f32x4){0.f, 0.f, 0.f, 0.f};

  for (int k0 = 0; k0 < K; k0 += 32) {
#pragma unroll
    for (int t = 0; t < 2; t++) {
      int u = t * 256 + tid;
      int row = u >> 2, c8 = (u & 3) * 8;
      int ra = tm + row; if (ra > M - 1) ra = M - 1;
      *(uint4*)&As[row * 32 + c8] = *(const uint4*)&A[(size_t)ra * K + k0 + c8];
      *(uint4*)&Bs[row * 32 + c8] = *(const uint4*)&BT[(size_t)(tn + row) * K + k0 + c8];
    }
    __syncthreads();
    s16x8 af[4], bfr[4];
#pragma unroll
    for (int mf = 0; mf < 4; mf++) af[mf] = *(const s16x8*)&As[(wm + mf * 16 + l) * 32 + q * 8];
#pragma unroll
    for (int nf = 0; nf < 4; nf++) bfr[nf] = *(const s16x8*)&Bs[(wn + nf * 16 + l) * 32 + q * 8];
#pragma unroll
    for (int mf = 0; mf < 4; mf++)
#pragma unroll
      for (int nf = 0; nf < 4; nf++)
        acc[mf][nf] = __builtin_amdgcn_mfma_f32_16x16x32_bf16(af[mf], bfr[nf], acc[mf][nf], 0, 0, 0);
    __syncthreads();
  }
  // C/D layout: col = lane&15, row = (lane>>4)*4 + reg   [m89-verified]
#pragma unroll
  for (int mf = 0; mf < 4; mf++) {
#pragma unroll
    for (int j = 0; j < 4; j++) {
      int r = tm + wm + mf * 16 + q * 4 + j;
      if (r < M) {
#pragma unroll
        for (int nf = 0; nf < 4; nf++) {
          int c = tn + wn + nf * 16 + l;
          float val = acc[mf][nf][j];
          ushort_t* op; int lc, w;
          if (c < b0)      { op = o0; lc = c;      w = b0; }
          else if (c < b1) { op = o1; lc = c - b0; w = b1 - b0; }
          else if (c < b2) { op = o2; lc = c - b1; w = b2 - b1; }
          else             { op = o3; lc = c - b2; w = NC - b2; val += bf2f(bias3[lc]); }
          op[(size_t)r * w + lc] = f2bf(val);
        }
      }
    }
  }
}

// ---------------- fused attention + aggregation, one block per dst node ----------------
// Barrier-free main loop: each wave owns edges j = e0+wave, +4, ... For each edge,
// the 64-lane butterfly leaves the full dot in EVERY lane, so the same wave applies
// w = exp(p/16) to its 4-features-per-lane slice of v[src] immediately. wsum is
// lane-uniform (no reduce needed). One barrier at the end to combine 4 waves.
__global__ __launch_bounds__(256)
void attn_kernel(const ushort_t* __restrict__ q, const ushort_t* __restrict__ k,
                 const ushort_t* __restrict__ v, const int* __restrict__ offs,
                 const int* __restrict__ srcS, ushort_t* __restrict__ h, int dout, int Nn) {
  int n = blockIdx.x;
  int tid = threadIdx.x;
  int lane = tid & 63, wave = tid >> 6;
  __shared__ float sacc[4][256];
  __shared__ float swsum[4];

  ushort4 qq = *(const ushort4*)(q + (size_t)n * 256 + lane * 4);
  float q0 = bf2f(qq.x), q1 = bf2f(qq.y), q2 = bf2f(qq.z), q3 = bf2f(qq.w);

  int e0 = offs[n], e1 = offs[n + 1];
  int fpl = dout >> 6;  // features per lane: 4 (dout=256) or 2 (dout=128)
  float acc0 = 0.f, acc1 = 0.f, acc2 = 0.f, acc3 = 0.f;
  float wsum = 0.f;

  for (int j = e0 + wave; j < e1; j += 4) {
    int s = srcS[j];
    if (s < 0) s = 0; if (s >= Nn) s = Nn - 1;
    ushort4 kk = *(const ushort4*)(k + (size_t)s * 256 + lane * 4);
    float p = q0 * bf2f(kk.x) + q1 * bf2f(kk.y) + q2 * bf2f(kk.z) + q3 * bf2f(kk.w);
#pragma unroll
    for (int o = 32; o > 0; o >>= 1) p += __shfl_xor(p, o);
    float w = __expf(p * 0.0625f);
    wsum += w;
    if (fpl == 4) {
      ushort4 vv = *(const ushort4*)(v + (size_t)s * 256 + lane * 4);
      acc0 += w * bf2f(vv.x); acc1 += w * bf2f(vv.y);
      acc2 += w * bf2f(vv.z); acc3 += w * bf2f(vv.w);
    } else {
      ushort2 vv = *(const ushort2*)(v + (size_t)s * 128 + lane * 2);
      acc0 += w * bf2f(vv.x); acc1 += w * bf2f(vv.y);
    }
  }
  if (fpl == 4) {
    sacc[wave][lane * 4 + 0] = acc0; sacc[wave][lane * 4 + 1] = acc1;
    sacc[wave][lane * 4 + 2] = acc2; sacc[wave][lane * 4 + 3] = acc3;
  } else {
    sacc[wave][lane * 2 + 0] = acc0; sacc[wave][lane * 2 + 1] = acc1;
  }
  if (lane == 0) swsum[wave] = wsum;  // wsum is lane-uniform
  __syncthreads();
  if (tid < dout) {
    float a = sacc[0][tid] + sacc[1][tid] + sacc[2][tid] + sacc[3][tid];
    float st = swsum[0] + swsum[1] + swsum[2] + swsum[3];
    size_t idx = (size_t)n * dout + tid;
    float hv = bf2f(h[idx]);  // h already holds x@Wr + b
    h[idx] = f2bf(hv + a / fmaxf(st, 1e-16f));
  }
}

// ---------------- BatchNorm ----------------
__global__ void bn_stats_kernel(const ushort_t* __restrict__ h, float* __restrict__ sum,
                                float* __restrict__ sumsq, int N, int F) {
  int col = threadIdx.x;
  float s = 0.f, s2 = 0.f;
  for (int r = blockIdx.x; r < N; r += gridDim.x) {
    float x = bf2f(h[(size_t)r * F + col]);
    s += x; s2 += x * x;
  }
  atomicAdd(&sum[col], s);
  atomicAdd(&sumsq[col], s2);
}

__global__ void bn_final_kernel(const float* __restrict__ sum, const float* __restrict__ sumsq,
                                const ushort_t* __restrict__ g, const ushort_t* __restrict__ be,
                                float* __restrict__ scale, float* __restrict__ shift, int N, int F) {
  int t = threadIdx.x;
  if (t < F) {
    float mu = sum[t] / (float)N;
    float var = sumsq[t] / (float)N - mu * mu;
    float sc = bf2f(g[t]) * rsqrtf(var + 1e-5f);
    scale[t] = sc;
    shift[t] = bf2f(be[t]) - mu * sc;
  }
}

__global__ void norm_relu_kernel(const ushort_t* __restrict__ h, const float* __restrict__ scale,
                                 const float* __restrict__ shift, ushort_t* __restrict__ x1,
                                 size_t total, int cmask) {
  for (size_t i = blockIdx.x * (size_t)blockDim.x + threadIdx.x; i < total;
       i += (size_t)gridDim.x * blockDim.x) {
    int c = (int)(i & (size_t)cmask);
    float vv = bf2f(h[i]) * scale[c] + shift[c];
    x1[i] = f2bf(relu_nanprop(vv));
  }
}

__global__ void final_kernel(const ushort_t* __restrict__ h, const float* __restrict__ scale,
                             const float* __restrict__ shift, const ushort_t* __restrict__ x0b,
                             void* __restrict__ out, const int* __restrict__ flagF, size_t total) {
  int f = flagF[0];
  for (size_t i = blockIdx.x * (size_t)blockDim.x + threadIdx.x; i < total;
       i += (size_t)gridDim.x * blockDim.x) {
    int c = (int)(i & 127);
    float vv = bf2f(h[i]) * scale[c] + shift[c] + bf2f(x0b[i]);
    vv = relu_nanprop(vv);
    if (f) ((float*)out)[i] = vv;
    else   ((ushort_t*)out)[i] = f2bf(vv);
  }
}

extern "C" void kernel_launch(void* const* d_in, const int* in_sizes, int n_in,
                              void* d_out, int out_size, void* d_ws, size_t ws_size,
                              hipStream_t stream) {
  const void* x0  = d_in[0];
  const void* edges = d_in[1];
  const void* Wq1 = d_in[2];
  const void* Wk1 = d_in[3];
  const void* Wv1 = d_in[4];
  const void* Wr1 = d_in[5];
  const void* b1  = d_in[6];
  const void* gw1 = d_in[7];
  const void* bw1 = d_in[8];
  const void* Wq2 = d_in[9];
  const void* Wk2 = d_in[10];
  const void* Wv2 = d_in[11];
  const void* Wr2 = d_in[12];
  const void* b2  = d_in[13];
  const void* gw2 = d_in[14];
  const void* bw2 = d_in[15];

  int N = in_sizes[0] / 128;
  int E = in_sizes[1] / 2;
  int NCHUNK = (N + 255) / 256;

  uintptr_t base = (uintptr_t)d_ws;
  auto carve = [&](size_t bytes) -> void* {
    uintptr_t p = base;
    base += (bytes + 255) & ~(size_t)255;
    return (void*)p;
  };
  ushort_t* x0b = (ushort_t*)carve((size_t)N * 128 * 2);
  ushort_t* qb = (ushort_t*)carve((size_t)N * 256 * 2);
  ushort_t* kb = (ushort_t*)carve((size_t)N * 256 * 2);
  ushort_t* vb = (ushort_t*)carve((size_t)N * 256 * 2);
  ushort_t* hb = (ushort_t*)carve((size_t)N * 256 * 2);
  ushort_t* x1 = (ushort_t*)carve((size_t)N * 256 * 2);
  ushort_t* wcat1 = (ushort_t*)carve((size_t)1024 * 128 * 2);
  ushort_t* wcat2 = (ushort_t*)carve((size_t)768 * 256 * 2);
  ushort_t* b1b  = (ushort_t*)carve(256 * 2);
  ushort_t* g1b  = (ushort_t*)carve(256 * 2);
  ushort_t* be1b = (ushort_t*)carve(256 * 2);
  ushort_t* b2b  = (ushort_t*)carve(128 * 2);
  ushort_t* g2b  = (ushort_t*)carve(128 * 2);
  ushort_t* be2b = (ushort_t*)carve(128 * 2);
  int* offs = (int*)carve((size_t)(N + 1) * 4);
  int* srcS = (int*)carve((size_t)E * 4);
  int* csum = (int*)carve(256 * 4);
  int* cpre = (int*)carve(256 * 4);
  int nzero = 2 * N + 64 + 1024;
  int* zreg = (int*)carve((size_t)nzero * 4);
  int* deg   = zreg;
  int* fill  = zreg + N;
  int* eflag = zreg + 2 * N;        // [0]=edge wide, [1]=float32 flag
  float* sum1 = (float*)(zreg + 2 * N + 64);
  float* sq1  = sum1 + 256;
  float* sum2 = sum1 + 512;
  float* sq2  = sum1 + 640;
  float* sc1 = (float*)carve(256 * 4);
  float* sh1 = (float*)carve(256 * 4);
  float* sc2 = (float*)carve(128 * 4);
  float* sh2 = (float*)carve(128 * 4);

  size_t needed = base - (uintptr_t)d_ws;
  if (needed > ws_size) return;

  int* fF = eflag + 1;

  zero_kernel<<<256, 256, 0, stream>>>(zreg, nzero);
  detect_kernel<<<1, 256, 0, stream>>>((const int*)edges, eflag, 2 * E);
  detect_f32_kernel<<<1, 256, 0, stream>>>((const unsigned int*)x0, fF, N * 128);

  cvt_kernel<<<4096, 256, 0, stream>>>(x0, x0b, N * 128, fF);
  cvt_params_kernel<<<5, 256, 0, stream>>>(b1, gw1, bw1, b2, gw2, bw2,
                                           b1b, g1b, be1b, b2b, g2b, be2b, 256, 128, fF);
  cvt_transpose4_kernel<<<512, 256, 0, stream>>>(Wq1, Wk1, Wv1, Wr1, wcat1, 128, 256, 256, fF);
  cvt_transpose4_kernel<<<512, 256, 0, stream>>>(Wq2, Wk2, Wv2, Wr2, wcat2, 256, 256, 128, fF);

  hist_kernel<<<1024, 256, 0, stream>>>(edges, eflag, deg, E, N);
  chunk_sum_kernel<<<NCHUNK, 256, 0, stream>>>(deg, csum, N);
  scan_small_kernel<<<1, 256, 0, stream>>>(csum, cpre, NCHUNK, offs, N);
  scan_final_kernel<<<NCHUNK, 256, 0, stream>>>(deg, cpre, offs, N);
  scatter_kernel<<<1024, 256, 0, stream>>>(edges, eflag, offs, fill, srcS, E, N);

  dim3 gA1((N + 127) / 128, 8);   // NC=1024
  dim3 gA2((N + 127) / 128, 6);   // NC=768
  // Layer 1: fused q|k|v|h GEMM
  gemm4_kernel<<<gA1, 256, 0, stream>>>(x0b, wcat1, qb, kb, vb, hb, b1b,
                                        N, 128, 1024, 256, 512, 768);
  attn_kernel<<<N, 256, 0, stream>>>(qb, kb, vb, offs, srcS, hb, 256, N);
  bn_stats_kernel<<<512, 256, 0, stream>>>(hb, sum1, sq1, N, 256);
  bn_final_kernel<<<1, 256, 0, stream>>>(sum1, sq1, g1b, be1b, sc1, sh1, N, 256);
  norm_relu_kernel<<<4096, 256, 0, stream>>>(hb, sc1, sh1, x1, (size_t)N * 256, 255);
  // Layer 2
  gemm4_kernel<<<gA2, 256, 0, stream>>>(x1, wcat2, qb, kb, vb, hb, b2b,
                                        N, 256, 768, 256, 512, 640);
  attn_kernel<<<N, 256, 0, stream>>>(qb, kb, vb, offs, srcS, hb, 128, N);
  bn_stats_kernel<<<512, 128, 0, stream>>>(hb, sum2, sq2, N, 128);
  bn_final_kernel<<<1, 128, 0, stream>>>(sum2, sq2, g2b, be2b, sc2, sh2, N, 128);
  final_kernel<<<4096, 256, 0, stream>>>(hb, sc2, sh2, x0b, d_out, fF, (size_t)N * 128);
}

// Round 7
// 656.244 us; speedup vs baseline: 1.6657x; 1.2385x over previous
//
#include <hip/hip_runtime.h>
#include <stdint.h>

typedef unsigned short ushort_t;

__device__ __forceinline__ float bf2f(unsigned short u) {
  union { unsigned int i; float f; } c; c.i = ((unsigned int)u) << 16; return c.f;
}
__device__ __forceinline__ unsigned short f2bf(float f) {
  union { float f; unsigned int i; } c; c.f = f;
  unsigned int r = c.i + 0x7FFFu + ((c.i >> 16) & 1u);
  return (unsigned short)(r >> 16);
}
// NaN-propagating relu (tripwire: NaN stays visible)
__device__ __forceinline__ float relu_nanprop(float v) { return (v < 0.f) ? 0.f : v; }

typedef __attribute__((ext_vector_type(8))) short s16x8;
typedef __attribute__((ext_vector_type(4))) float f32x4;

// ---------------- zero scratch ints ----------------
__global__ void zero_kernel(int* __restrict__ p, int n) {
  for (int i = blockIdx.x * blockDim.x + threadIdx.x; i < n; i += gridDim.x * blockDim.x)
    p[i] = 0;
}

// ---------------- float32-vs-bf16 detection on x0 ----------------
__global__ void detect_f32_kernel(const unsigned int* __restrict__ x, int* __restrict__ flagF, int nw) {
  __shared__ int cnt;
  if (threadIdx.x == 0) cnt = 0;
  __syncthreads();
  int local = 0;
  for (int i = threadIdx.x; i < 4096 && i < nw; i += blockDim.x) {
    unsigned int low = x[i] & 0xFFFFu;
    unsigned int e = (low >> 7) & 0xFFu;
    if (low != 0u && (e < 96u || e > 144u)) local++;
  }
  atomicAdd(&cnt, local);
  __syncthreads();
  if (threadIdx.x == 0) flagF[0] = (cnt > 1024) ? 1 : 0;  // 1 => float32 inputs
}

// ---------------- edge dtype detection (int64 vs int32) ----------------
__global__ void detect_kernel(const int* __restrict__ e32, int* __restrict__ flag, int n32) {
  __shared__ int any;
  if (threadIdx.x == 0) any = 0;
  __syncthreads();
  for (int i = threadIdx.x; i < 4096; i += blockDim.x) {
    int idx = 2 * i + 1;
    if (idx < n32 && e32[idx] != 0) any = 1;
  }
  __syncthreads();
  if (threadIdx.x == 0) flag[0] = (any == 0) ? 1 : 0;  // 1 => int64
}

__device__ __forceinline__ int edge_at(const void* edges, int wide, int idx) {
  if (wide) return (int)((const long long*)edges)[idx];
  return ((const int*)edges)[idx];
}

// ---------------- convert input (float32 or bf16) -> bf16 ----------------
__global__ void cvt_kernel(const void* __restrict__ in, ushort_t* __restrict__ out,
                           int n, const int* __restrict__ flagF) {
  int f = flagF[0];
  for (int i = blockIdx.x * blockDim.x + threadIdx.x; i < n; i += gridDim.x * blockDim.x)
    out[i] = f ? f2bf(((const float*)in)[i]) : ((const ushort_t*)in)[i];
}

// 6 small param vectors in one launch
__global__ void cvt_params_kernel(const void* p0, const void* p1, const void* p2,
                                  const void* p3, const void* p4, const void* p5,
                                  ushort_t* o0, ushort_t* o1, ushort_t* o2,
                                  ushort_t* o3, ushort_t* o4, ushort_t* o5,
                                  int n0, int n3, const int* __restrict__ flagF) {
  int f = flagF[0];
  int t = blockIdx.x * blockDim.x + threadIdx.x;
  const void* ins[6] = {p0, p1, p2, p3, p4, p5};
  ushort_t* outs[6] = {o0, o1, o2, o3, o4, o5};
  int sizes[6] = {n0, n0, n0, n3, n3, n3};
  int off = 0;
  for (int s = 0; s < 6; s++) {
    int i = t - off;
    if (i >= 0 && i < sizes[s])
      outs[s][i] = f ? f2bf(((const float*)ins[s])[i]) : ((const ushort_t*)ins[s])[i];
    off += sizes[s];
  }
}

// ---------------- convert + transpose 4 weights into one cat buffer ----------------
__global__ void cvt_transpose4_kernel(const void* W0, const void* W1, const void* W2, const void* W3,
                                      ushort_t* __restrict__ out, int K, int C01, int C23,
                                      const int* __restrict__ flagF) {
  int f = flagF[0];
  int per01 = K * C01, per23 = K * C23;
  int total = 2 * per01 + 2 * per23;
  for (int i = blockIdx.x * blockDim.x + threadIdx.x; i < total; i += gridDim.x * blockDim.x) {
    const void* W; int rem, C, rowoff;
    if (i < per01)                { W = W0; rem = i;                 C = C01; rowoff = 0; }
    else if (i < 2 * per01)       { W = W1; rem = i - per01;         C = C01; rowoff = C01; }
    else if (i < 2 * per01 + per23){ W = W2; rem = i - 2 * per01;    C = C23; rowoff = 2 * C01; }
    else                          { W = W3; rem = i - 2 * per01 - per23; C = C23; rowoff = 2 * C01 + C23; }
    int k = rem / C, c = rem - k * C;
    ushort_t v = f ? f2bf(((const float*)W)[rem]) : ((const ushort_t*)W)[rem];
    out[(size_t)(rowoff + c) * K + k] = v;
  }
}

// ---------------- CSR build ----------------
__global__ void hist_kernel(const void* __restrict__ edges, const int* __restrict__ flag,
                            int* __restrict__ deg, int E, int Nn) {
  int wide = flag[0];
  for (int e = blockIdx.x * blockDim.x + threadIdx.x; e < E; e += gridDim.x * blockDim.x) {
    int d = edge_at(edges, wide, E + e);
    if (d < 0) d = 0; if (d >= Nn) d = Nn - 1;
    atomicAdd(&deg[d], 1);
  }
}

// 3-phase parallel scan (chunk = 256): supports N <= 65536
__global__ void chunk_sum_kernel(const int* __restrict__ deg, int* __restrict__ csum, int n) {
  int b = blockIdx.x, t = threadIdx.x, i = b * 256 + t;
  int v = (i < n) ? deg[i] : 0;
  __shared__ int ws[4];
#pragma unroll
  for (int o = 32; o > 0; o >>= 1) v += __shfl_down(v, o);
  if ((t & 63) == 0) ws[t >> 6] = v;
  __syncthreads();
  if (t == 0) csum[b] = ws[0] + ws[1] + ws[2] + ws[3];
}

__global__ void scan_small_kernel(const int* __restrict__ csum, int* __restrict__ cpre,
                                  int nc, int* __restrict__ offs, int N) {
  __shared__ int tmp[256];
  int t = threadIdx.x;
  int v = (t < nc) ? csum[t] : 0;
  tmp[t] = v;
  __syncthreads();
  for (int off = 1; off < 256; off <<= 1) {
    int x = (t >= off) ? tmp[t - off] : 0;
    __syncthreads();
    tmp[t] += x;
    __syncthreads();
  }
  if (t < nc) cpre[t] = tmp[t] - v;
  if (t == 255) offs[N] = tmp[255];
}

__global__ void scan_final_kernel(const int* __restrict__ deg, const int* __restrict__ cpre,
                                  int* __restrict__ offs, int n) {
  int b = blockIdx.x, t = threadIdx.x, i = b * 256 + t;
  __shared__ int tmp[256];
  int v = (i < n) ? deg[i] : 0;
  tmp[t] = v;
  __syncthreads();
  for (int off = 1; off < 256; off <<= 1) {
    int x = (t >= off) ? tmp[t - off] : 0;
    __syncthreads();
    tmp[t] += x;
    __syncthreads();
  }
  if (i < n) offs[i] = cpre[b] + tmp[t] - v;
}

__global__ void scatter_kernel(const void* __restrict__ edges, const int* __restrict__ flag,
                               const int* __restrict__ offs, int* __restrict__ fill,
                               int* __restrict__ srcS, int E, int Nn) {
  int wide = flag[0];
  for (int e = blockIdx.x * blockDim.x + threadIdx.x; e < E; e += gridDim.x * blockDim.x) {
    int s = edge_at(edges, wide, e);
    int d = edge_at(edges, wide, E + e);
    if (d < 0) d = 0; if (d >= Nn) d = Nn - 1;
    if (s < 0) s = 0; if (s >= Nn) s = Nn - 1;
    int p = offs[d] + atomicAdd(&fill[d], 1);
    if (p < 0) p = 0; if (p >= E) p = E - 1;
    srcS[p] = s;
  }
}

// ---------------- fused 4-way GEMM: [q|k|v|h] = A @ Wcat, bf16 in/out ----------------
__global__ __launch_bounds__(256)
void gemm4_kernel(const ushort_t* __restrict__ A, const ushort_t* __restrict__ BT,
                  ushort_t* __restrict__ o0, ushort_t* __restrict__ o1,
                  ushort_t* __restrict__ o2, ushort_t* __restrict__ o3,
                  const ushort_t* __restrict__ bias3,
                  int M, int K, int NC, int b0, int b1, int b2) {
  __shared__ __align__(16) ushort_t As[128 * 32];
  __shared__ __align__(16) ushort_t Bs[128 * 32];
  int tid = threadIdx.x;
  int lane = tid & 63, wave = tid >> 6;
  int tm = blockIdx.x * 128, tn = blockIdx.y * 128;
  int wm = (wave >> 1) * 64, wn = (wave & 1) * 64;
  int q = lane >> 4, l = lane & 15;
  f32x4 acc[4][4];
#pragma unroll
  for (int a = 0; a < 4; a++)
#pragma unroll
    for (int b = 0; b < 4; b++) acc[a][b] = (f32x4){0.f, 0.f, 0.f, 0.f};

  for (int k0 = 0; k0 < K; k0 += 32) {
#pragma unroll
    for (int t = 0; t < 2; t++) {
      int u = t * 256 + tid;
      int row = u >> 2, c8 = (u & 3) * 8;
      int ra = tm + row; if (ra > M - 1) ra = M - 1;
      *(uint4*)&As[row * 32 + c8] = *(const uint4*)&A[(size_t)ra * K + k0 + c8];
      *(uint4*)&Bs[row * 32 + c8] = *(const uint4*)&BT[(size_t)(tn + row) * K + k0 + c8];
    }
    __syncthreads();
    s16x8 af[4], bfr[4];
#pragma unroll
    for (int mf = 0; mf < 4; mf++) af[mf] = *(const s16x8*)&As[(wm + mf * 16 + l) * 32 + q * 8];
#pragma unroll
    for (int nf = 0; nf < 4; nf++) bfr[nf] = *(const s16x8*)&Bs[(wn + nf * 16 + l) * 32 + q * 8];
#pragma unroll
    for (int mf = 0; mf < 4; mf++)
#pragma unroll
      for (int nf = 0; nf < 4; nf++)
        acc[mf][nf] = __builtin_amdgcn_mfma_f32_16x16x32_bf16(af[mf], bfr[nf], acc[mf][nf], 0, 0, 0);
    __syncthreads();
  }
  // C/D layout: col = lane&15, row = (lane>>4)*4 + reg   [m89-verified]
#pragma unroll
  for (int mf = 0; mf < 4; mf++) {
#pragma unroll
    for (int j = 0; j < 4; j++) {
      int r = tm + wm + mf * 16 + q * 4 + j;
      if (r < M) {
#pragma unroll
        for (int nf = 0; nf < 4; nf++) {
          int c = tn + wn + nf * 16 + l;
          float val = acc[mf][nf][j];
          ushort_t* op; int lc, w;
          if (c < b0)      { op = o0; lc = c;      w = b0; }
          else if (c < b1) { op = o1; lc = c - b0; w = b1 - b0; }
          else if (c < b2) { op = o2; lc = c - b1; w = b2 - b1; }
          else             { op = o3; lc = c - b2; w = NC - b2; val += bf2f(bias3[lc]); }
          op[(size_t)r * w + lc] = f2bf(val);
        }
      }
    }
  }
}

// ---------------- fused attention + aggregation, one WAVE per dst node ----------------
// Each wave owns a full node: q row in regs (4 f/lane), edge loop unrolled x4 so
// 4 srcS + 4 k-rows + 4 v-rows are in flight simultaneously (latency/MLP /4).
// Butterfly leaves full dot in every lane; w and wsum are lane-uniform; the wave
// accumulates the whole 256(128)-wide output row in registers. Zero barriers, zero LDS.
__global__ __launch_bounds__(256)
void attn_kernel(const ushort_t* __restrict__ q, const ushort_t* __restrict__ k,
                 const ushort_t* __restrict__ v, const int* __restrict__ offs,
                 const int* __restrict__ srcS, ushort_t* __restrict__ h, int dout, int Nn) {
  int lane = threadIdx.x & 63, wave = threadIdx.x >> 6;
  int n = blockIdx.x * 4 + wave;
  if (n >= Nn) return;

  ushort4 qq = *(const ushort4*)(q + (size_t)n * 256 + lane * 4);
  float q0 = bf2f(qq.x), q1 = bf2f(qq.y), q2 = bf2f(qq.z), q3 = bf2f(qq.w);

  int e0 = offs[n], e1 = offs[n + 1];
  float a0 = 0.f, a1 = 0.f, a2 = 0.f, a3 = 0.f, wsum = 0.f;
  int j = e0;

  if (dout == 256) {
    for (; j + 4 <= e1; j += 4) {
      int s0 = srcS[j], s1 = srcS[j + 1], s2 = srcS[j + 2], s3 = srcS[j + 3];
      if (s0 < 0 || s0 >= Nn) s0 = 0;
      if (s1 < 0 || s1 >= Nn) s1 = 0;
      if (s2 < 0 || s2 >= Nn) s2 = 0;
      if (s3 < 0 || s3 >= Nn) s3 = 0;
      ushort4 k0 = *(const ushort4*)(k + (size_t)s0 * 256 + lane * 4);
      ushort4 k1 = *(const ushort4*)(k + (size_t)s1 * 256 + lane * 4);
      ushort4 k2 = *(const ushort4*)(k + (size_t)s2 * 256 + lane * 4);
      ushort4 k3 = *(const ushort4*)(k + (size_t)s3 * 256 + lane * 4);
      ushort4 v0 = *(const ushort4*)(v + (size_t)s0 * 256 + lane * 4);
      ushort4 v1 = *(const ushort4*)(v + (size_t)s1 * 256 + lane * 4);
      ushort4 v2 = *(const ushort4*)(v + (size_t)s2 * 256 + lane * 4);
      ushort4 v3 = *(const ushort4*)(v + (size_t)s3 * 256 + lane * 4);
      float p0 = q0 * bf2f(k0.x) + q1 * bf2f(k0.y) + q2 * bf2f(k0.z) + q3 * bf2f(k0.w);
      float p1 = q0 * bf2f(k1.x) + q1 * bf2f(k1.y) + q2 * bf2f(k1.z) + q3 * bf2f(k1.w);
      float p2 = q0 * bf2f(k2.x) + q1 * bf2f(k2.y) + q2 * bf2f(k2.z) + q3 * bf2f(k2.w);
      float p3 = q0 * bf2f(k3.x) + q1 * bf2f(k3.y) + q2 * bf2f(k3.z) + q3 * bf2f(k3.w);
#pragma unroll
      for (int o = 32; o > 0; o >>= 1) {
        p0 += __shfl_xor(p0, o); p1 += __shfl_xor(p1, o);
        p2 += __shfl_xor(p2, o); p3 += __shfl_xor(p3, o);
      }
      float w0 = __expf(p0 * 0.0625f), w1 = __expf(p1 * 0.0625f);
      float w2 = __expf(p2 * 0.0625f), w3 = __expf(p3 * 0.0625f);
      wsum += (w0 + w1) + (w2 + w3);
      a0 += w0 * bf2f(v0.x) + w1 * bf2f(v1.x) + w2 * bf2f(v2.x) + w3 * bf2f(v3.x);
      a1 += w0 * bf2f(v0.y) + w1 * bf2f(v1.y) + w2 * bf2f(v2.y) + w3 * bf2f(v3.y);
      a2 += w0 * bf2f(v0.z) + w1 * bf2f(v1.z) + w2 * bf2f(v2.z) + w3 * bf2f(v3.z);
      a3 += w0 * bf2f(v0.w) + w1 * bf2f(v1.w) + w2 * bf2f(v2.w) + w3 * bf2f(v3.w);
    }
    for (; j < e1; j++) {
      int s = srcS[j];
      if (s < 0 || s >= Nn) s = 0;
      ushort4 kk = *(const ushort4*)(k + (size_t)s * 256 + lane * 4);
      ushort4 vv = *(const ushort4*)(v + (size_t)s * 256 + lane * 4);
      float p = q0 * bf2f(kk.x) + q1 * bf2f(kk.y) + q2 * bf2f(kk.z) + q3 * bf2f(kk.w);
#pragma unroll
      for (int o = 32; o > 0; o >>= 1) p += __shfl_xor(p, o);
      float w = __expf(p * 0.0625f);
      wsum += w;
      a0 += w * bf2f(vv.x); a1 += w * bf2f(vv.y);
      a2 += w * bf2f(vv.z); a3 += w * bf2f(vv.w);
    }
    float inv = 1.f / fmaxf(wsum, 1e-16f);
    size_t idx = (size_t)n * 256 + lane * 4;
    ushort4 hh = *(const ushort4*)(h + idx);
    ushort4 ho;
    ho.x = f2bf(bf2f(hh.x) + a0 * inv);
    ho.y = f2bf(bf2f(hh.y) + a1 * inv);
    ho.z = f2bf(bf2f(hh.z) + a2 * inv);
    ho.w = f2bf(bf2f(hh.w) + a3 * inv);
    *(ushort4*)(h + idx) = ho;
  } else {  // dout == 128: 2 features per lane
    for (; j + 4 <= e1; j += 4) {
      int s0 = srcS[j], s1 = srcS[j + 1], s2 = srcS[j + 2], s3 = srcS[j + 3];
      if (s0 < 0 || s0 >= Nn) s0 = 0;
      if (s1 < 0 || s1 >= Nn) s1 = 0;
      if (s2 < 0 || s2 >= Nn) s2 = 0;
      if (s3 < 0 || s3 >= Nn) s3 = 0;
      ushort4 k0 = *(const ushort4*)(k + (size_t)s0 * 256 + lane * 4);
      ushort4 k1 = *(const ushort4*)(k + (size_t)s1 * 256 + lane * 4);
      ushort4 k2 = *(const ushort4*)(k + (size_t)s2 * 256 + lane * 4);
      ushort4 k3 = *(const ushort4*)(k + (size_t)s3 * 256 + lane * 4);
      ushort2 v0 = *(const ushort2*)(v + (size_t)s0 * 128 + lane * 2);
      ushort2 v1 = *(const ushort2*)(v + (size_t)s1 * 128 + lane * 2);
      ushort2 v2 = *(const ushort2*)(v + (size_t)s2 * 128 + lane * 2);
      ushort2 v3 = *(const ushort2*)(v + (size_t)s3 * 128 + lane * 2);
      float p0 = q0 * bf2f(k0.x) + q1 * bf2f(k0.y) + q2 * bf2f(k0.z) + q3 * bf2f(k0.w);
      float p1 = q0 * bf2f(k1.x) + q1 * bf2f(k1.y) + q2 * bf2f(k1.z) + q3 * bf2f(k1.w);
      float p2 = q0 * bf2f(k2.x) + q1 * bf2f(k2.y) + q2 * bf2f(k2.z) + q3 * bf2f(k2.w);
      float p3 = q0 * bf2f(k3.x) + q1 * bf2f(k3.y) + q2 * bf2f(k3.z) + q3 * bf2f(k3.w);
#pragma unroll
      for (int o = 32; o > 0; o >>= 1) {
        p0 += __shfl_xor(p0, o); p1 += __shfl_xor(p1, o);
        p2 += __shfl_xor(p2, o); p3 += __shfl_xor(p3, o);
      }
      float w0 = __expf(p0 * 0.0625f), w1 = __expf(p1 * 0.0625f);
      float w2 = __expf(p2 * 0.0625f), w3 = __expf(p3 * 0.0625f);
      wsum += (w0 + w1) + (w2 + w3);
      a0 += w0 * bf2f(v0.x) + w1 * bf2f(v1.x) + w2 * bf2f(v2.x) + w3 * bf2f(v3.x);
      a1 += w0 * bf2f(v0.y) + w1 * bf2f(v1.y) + w2 * bf2f(v2.y) + w3 * bf2f(v3.y);
    }
    for (; j < e1; j++) {
      int s = srcS[j];
      if (s < 0 || s >= Nn) s = 0;
      ushort4 kk = *(const ushort4*)(k + (size_t)s * 256 + lane * 4);
      ushort2 vv = *(const ushort2*)(v + (size_t)s * 128 + lane * 2);
      float p = q0 * bf2f(kk.x) + q1 * bf2f(kk.y) + q2 * bf2f(kk.z) + q3 * bf2f(kk.w);
#pragma unroll
      for (int o = 32; o > 0; o >>= 1) p += __shfl_xor(p, o);
      float w = __expf(p * 0.0625f);
      wsum += w;
      a0 += w * bf2f(vv.x); a1 += w * bf2f(vv.y);
    }
    float inv = 1.f / fmaxf(wsum, 1e-16f);
    size_t idx = (size_t)n * 128 + lane * 2;
    ushort2 hh = *(const ushort2*)(h + idx);
    ushort2 ho;
    ho.x = f2bf(bf2f(hh.x) + a0 * inv);
    ho.y = f2bf(bf2f(hh.y) + a1 * inv);
    *(ushort2*)(h + idx) = ho;
  }
}

// ---------------- BatchNorm ----------------
__global__ void bn_stats_kernel(const ushort_t* __restrict__ h, float* __restrict__ sum,
                                float* __restrict__ sumsq, int N, int F) {
  int col = threadIdx.x;
  float s = 0.f, s2 = 0.f;
  for (int r = blockIdx.x; r < N; r += gridDim.x) {
    float x = bf2f(h[(size_t)r * F + col]);
    s += x; s2 += x * x;
  }
  atomicAdd(&sum[col], s);
  atomicAdd(&sumsq[col], s2);
}

__global__ void bn_final_kernel(const float* __restrict__ sum, const float* __restrict__ sumsq,
                                const ushort_t* __restrict__ g, const ushort_t* __restrict__ be,
                                float* __restrict__ scale, float* __restrict__ shift, int N, int F) {
  int t = threadIdx.x;
  if (t < F) {
    float mu = sum[t] / (float)N;
    float var = sumsq[t] / (float)N - mu * mu;
    float sc = bf2f(g[t]) * rsqrtf(var + 1e-5f);
    scale[t] = sc;
    shift[t] = bf2f(be[t]) - mu * sc;
  }
}

__global__ void norm_relu_kernel(const ushort_t* __restrict__ h, const float* __restrict__ scale,
                                 const float* __restrict__ shift, ushort_t* __restrict__ x1,
                                 size_t total, int cmask) {
  for (size_t i = blockIdx.x * (size_t)blockDim.x + threadIdx.x; i < total;
       i += (size_t)gridDim.x * blockDim.x) {
    int c = (int)(i & (size_t)cmask);
    float vv = bf2f(h[i]) * scale[c] + shift[c];
    x1[i] = f2bf(relu_nanprop(vv));
  }
}

__global__ void final_kernel(const ushort_t* __restrict__ h, const float* __restrict__ scale,
                             const float* __restrict__ shift, const ushort_t* __restrict__ x0b,
                             void* __restrict__ out, const int* __restrict__ flagF, size_t total) {
  int f = flagF[0];
  for (size_t i = blockIdx.x * (size_t)blockDim.x + threadIdx.x; i < total;
       i += (size_t)gridDim.x * blockDim.x) {
    int c = (int)(i & 127);
    float vv = bf2f(h[i]) * scale[c] + shift[c] + bf2f(x0b[i]);
    vv = relu_nanprop(vv);
    if (f) ((float*)out)[i] = vv;
    else   ((ushort_t*)out)[i] = f2bf(vv);
  }
}

extern "C" void kernel_launch(void* const* d_in, const int* in_sizes, int n_in,
                              void* d_out, int out_size, void* d_ws, size_t ws_size,
                              hipStream_t stream) {
  const void* x0  = d_in[0];
  const void* edges = d_in[1];
  const void* Wq1 = d_in[2];
  const void* Wk1 = d_in[3];
  const void* Wv1 = d_in[4];
  const void* Wr1 = d_in[5];
  const void* b1  = d_in[6];
  const void* gw1 = d_in[7];
  const void* bw1 = d_in[8];
  const void* Wq2 = d_in[9];
  const void* Wk2 = d_in[10];
  const void* Wv2 = d_in[11];
  const void* Wr2 = d_in[12];
  const void* b2  = d_in[13];
  const void* gw2 = d_in[14];
  const void* bw2 = d_in[15];

  int N = in_sizes[0] / 128;
  int E = in_sizes[1] / 2;
  int NCHUNK = (N + 255) / 256;

  uintptr_t base = (uintptr_t)d_ws;
  auto carve = [&](size_t bytes) -> void* {
    uintptr_t p = base;
    base += (bytes + 255) & ~(size_t)255;
    return (void*)p;
  };
  ushort_t* x0b = (ushort_t*)carve((size_t)N * 128 * 2);
  ushort_t* qb = (ushort_t*)carve((size_t)N * 256 * 2);
  ushort_t* kb = (ushort_t*)carve((size_t)N * 256 * 2);
  ushort_t* vb = (ushort_t*)carve((size_t)N * 256 * 2);
  ushort_t* hb = (ushort_t*)carve((size_t)N * 256 * 2);
  ushort_t* x1 = (ushort_t*)carve((size_t)N * 256 * 2);
  ushort_t* wcat1 = (ushort_t*)carve((size_t)1024 * 128 * 2);
  ushort_t* wcat2 = (ushort_t*)carve((size_t)768 * 256 * 2);
  ushort_t* b1b  = (ushort_t*)carve(256 * 2);
  ushort_t* g1b  = (ushort_t*)carve(256 * 2);
  ushort_t* be1b = (ushort_t*)carve(256 * 2);
  ushort_t* b2b  = (ushort_t*)carve(128 * 2);
  ushort_t* g2b  = (ushort_t*)carve(128 * 2);
  ushort_t* be2b = (ushort_t*)carve(128 * 2);
  int* offs = (int*)carve((size_t)(N + 1) * 4);
  int* srcS = (int*)carve((size_t)E * 4);
  int* csum = (int*)carve(256 * 4);
  int* cpre = (int*)carve(256 * 4);
  int nzero = 2 * N + 64 + 1024;
  int* zreg = (int*)carve((size_t)nzero * 4);
  int* deg   = zreg;
  int* fill  = zreg + N;
  int* eflag = zreg + 2 * N;        // [0]=edge wide, [1]=float32 flag
  float* sum1 = (float*)(zreg + 2 * N + 64);
  float* sq1  = sum1 + 256;
  float* sum2 = sum1 + 512;
  float* sq2  = sum1 + 640;
  float* sc1 = (float*)carve(256 * 4);
  float* sh1 = (float*)carve(256 * 4);
  float* sc2 = (float*)carve(128 * 4);
  float* sh2 = (float*)carve(128 * 4);

  size_t needed = base - (uintptr_t)d_ws;
  if (needed > ws_size) return;

  int* fF = eflag + 1;

  zero_kernel<<<256, 256, 0, stream>>>(zreg, nzero);
  detect_kernel<<<1, 256, 0, stream>>>((const int*)edges, eflag, 2 * E);
  detect_f32_kernel<<<1, 256, 0, stream>>>((const unsigned int*)x0, fF, N * 128);

  cvt_kernel<<<4096, 256, 0, stream>>>(x0, x0b, N * 128, fF);
  cvt_params_kernel<<<5, 256, 0, stream>>>(b1, gw1, bw1, b2, gw2, bw2,
                                           b1b, g1b, be1b, b2b, g2b, be2b, 256, 128, fF);
  cvt_transpose4_kernel<<<512, 256, 0, stream>>>(Wq1, Wk1, Wv1, Wr1, wcat1, 128, 256, 256, fF);
  cvt_transpose4_kernel<<<512, 256, 0, stream>>>(Wq2, Wk2, Wv2, Wr2, wcat2, 256, 256, 128, fF);

  hist_kernel<<<1024, 256, 0, stream>>>(edges, eflag, deg, E, N);
  chunk_sum_kernel<<<NCHUNK, 256, 0, stream>>>(deg, csum, N);
  scan_small_kernel<<<1, 256, 0, stream>>>(csum, cpre, NCHUNK, offs, N);
  scan_final_kernel<<<NCHUNK, 256, 0, stream>>>(deg, cpre, offs, N);
  scatter_kernel<<<1024, 256, 0, stream>>>(edges, eflag, offs, fill, srcS, E, N);

  dim3 gA1((N + 127) / 128, 8);   // NC=1024
  dim3 gA2((N + 127) / 128, 6);   // NC=768
  int gAttn = (N + 3) / 4;        // one wave per node
  // Layer 1: fused q|k|v|h GEMM
  gemm4_kernel<<<gA1, 256, 0, stream>>>(x0b, wcat1, qb, kb, vb, hb, b1b,
                                        N, 128, 1024, 256, 512, 768);
  attn_kernel<<<gAttn, 256, 0, stream>>>(qb, kb, vb, offs, srcS, hb, 256, N);
  bn_stats_kernel<<<512, 256, 0, stream>>>(hb, sum1, sq1, N, 256);
  bn_final_kernel<<<1, 256, 0, stream>>>(sum1, sq1, g1b, be1b, sc1, sh1, N, 256);
  norm_relu_kernel<<<4096, 256, 0, stream>>>(hb, sc1, sh1, x1, (size_t)N * 256, 255);
  // Layer 2
  gemm4_kernel<<<gA2, 256, 0, stream>>>(x1, wcat2, qb, kb, vb, hb, b2b,
                                        N, 256, 768, 256, 512, 640);
  attn_kernel<<<gAttn, 256, 0, stream>>>(qb, kb, vb, offs, srcS, hb, 128, N);
  bn_stats_kernel<<<512, 128, 0, stream>>>(hb, sum2, sq2, N, 128);
  bn_final_kernel<<<1, 128, 0, stream>>>(sum2, sq2, g2b, be2b, sc2, sh2, N, 128);
  final_kernel<<<4096, 256, 0, stream>>>(hb, sc2, sh2, x0b, d_out, fF, (size_t)N * 128);
}